// Round 5
// baseline (2242.400 us; speedup 1.0000x reference)
//
#include <hip/hip_runtime.h>
#include <stdint.h>

// IntegratedNCA: 64 NCA steps. B=8, CH=16, H=W=96, HID=128, WDIM=128.
// Multi-launch (per-step kernel = the global sync). Phase B (life masking)
// fused into the NEXT step's staging: X_s = Y_{s-1} * life_{s-1} in LDS.
//
// R23 = R22 (16x8 tile, 2 px/lane, split-pipe MLP) with the SCRATCH BUG fixed:
//   R22 post-mortem: perceive() took float4*/v2f* out-params; even inlined,
//   the address-taken local arrays defeated SROA -> xc/xp/pp lived in
//   SCRATCH (rule #20). Evidence: WRITE_SIZE 54.2MB/dispatch (= 384B/thread
//   x 147K threads), FETCH 27.4MB, VGPR_Count 84 << ~130 live set, 31ms
//   replay dispatch. Fix: straight-line macro perception (R21 code shape,
//   A/B-suffixed named arrays, all indices compile-time constants).
//   2-px/lane amortization theory unchanged: per-wave weight stream (w1
//   s_loads on waves 0-1, LDS broadcasts on waves 2-3, w2t s_loads) now
//   covers 2x pixels -> per-pixel stream cost halves on both pipes; grid
//   576 blocks <= 3/CU resident -> one-round steps.
// LDS: monolithic sm[] carve; red2[2][16][128] (16KB) aliases xs+w1s head
// (both dead post-MLP). Total ~24.8KB. launch_bounds(256,3) (VGPR cap 170).
// nca_final keeps the old 16x4 geometry (1152 blocks) -- untouched.
//
// PRNG: JAX threefry, jax_threefry_partitionable=True (green R2/R5-R17):
//   split: key[i]  = threefry2x32(0,42, 0, i)   (host-side, passed as args)
//   bits : bits[p] = o0^o1, (o0,o1)=threefry2x32(key, 0, p); uniform<0.5 <=> bits>>31==0

#define CHN 16
#define HIDN 128
#define WD 128
#define NB 8
#define NH 96
#define NW 96
#define NSTEPS 64
#define PLANE (NH*NW)          // 9216
#define NT 256

// ---- final-kernel tile geometry ----
#define TW 16
#define TH 4
#define TILES_X (NW/TW)        // 6
#define TILES_Y (NH/TH)        // 24
#define TPI (TILES_X*TILES_Y)  // 144
#define NBLK (NB*TPI)          // 1152

// ---- step-kernel tile geometry (16x8, 2 px/lane) ----
#define STW 16
#define STH 8
#define S_TILES_X (NW/STW)     // 6
#define S_TILES_Y (NH/STH)     // 12
#define S_TPI (S_TILES_X*S_TILES_Y) // 72
#define S_NBLK (NB*S_TPI)      // 576
#define SHW (STH+2)            // 10 staged rows (halo 1)
#define SWW (STW+2)            // 18 staged cols (halo 1)
#define S_NF4 (SHW*SWW*4)      // 720 staged float4s
#define XS_F (SHW*SWW*20)      // 3600 floats (NHWC pad 20)
#define W1S_F (64*32)          // 2048 floats (upper w1 half)

typedef float v2f __attribute__((ext_vector_type(2)));

__host__ __device__ __forceinline__ uint32_t rotl(uint32_t v, int d){ return (v<<d)|(v>>(32-d)); }

__host__ __device__ __forceinline__ void threefry2x32(uint32_t k0, uint32_t k1,
                                                      uint32_t x0, uint32_t x1,
                                                      uint32_t &o0, uint32_t &o1){
  uint32_t k2 = k0 ^ k1 ^ 0x1BD11BDAu;
  x0 += k0; x1 += k1;
  x0 += x1; x1 = rotl(x1,13); x1 ^= x0;
  x0 += x1; x1 = rotl(x1,15); x1 ^= x0;
  x0 += x1; x1 = rotl(x1,26); x1 ^= x0;
  x0 += x1; x1 = rotl(x1, 6); x1 ^= x0;
  x0 += k1; x1 += k2 + 1u;
  x0 += x1; x1 = rotl(x1,17); x1 ^= x0;
  x0 += x1; x1 = rotl(x1,29); x1 ^= x0;
  x0 += x1; x1 = rotl(x1,16); x1 ^= x0;
  x0 += x1; x1 = rotl(x1,24); x1 ^= x0;
  x0 += k2; x1 += k0 + 2u;
  x0 += x1; x1 = rotl(x1,13); x1 ^= x0;
  x0 += x1; x1 = rotl(x1,15); x1 ^= x0;
  x0 += x1; x1 = rotl(x1,26); x1 ^= x0;
  x0 += x1; x1 = rotl(x1, 6); x1 ^= x0;
  x0 += k0; x1 += k1 + 3u;
  x0 += x1; x1 = rotl(x1,17); x1 ^= x0;
  x0 += x1; x1 = rotl(x1,29); x1 ^= x0;
  x0 += x1; x1 = rotl(x1,16); x1 ^= x0;
  x0 += x1; x1 = rotl(x1,24); x1 ^= x0;
  x0 += k1; x1 += k2 + 4u;
  x0 += x1; x1 = rotl(x1,13); x1 ^= x0;
  x0 += x1; x1 = rotl(x1,15); x1 ^= x0;
  x0 += x1; x1 = rotl(x1,26); x1 ^= x0;
  x0 += x1; x1 = rotl(x1, 6); x1 ^= x0;
  x0 += k2; x1 += k0 + 5u;
  o0 = x0; o1 = x1;
}

// Pre: w1eff[128][32] natural layout (cols 0..15 = W1[:, :16]; cols 16..31 =
// folded perception pairs P[cc] = W1[:,16+2cc]+W1[:,17+2cc]) -- v2f-readable.
// w2t[128][16] = W2^T, c1[8][128] = b1 + W1[:,48:176].w[b].
__global__ __launch_bounds__(256) void nca_pre(
    const float* __restrict__ w, const float* __restrict__ W1,
    const float* __restrict__ b1, const float* __restrict__ W2,
    float* __restrict__ w1eff, float* __restrict__ w2t, float* __restrict__ c1)
{
  const int b = blockIdx.x, t = threadIdx.x;
  if (b == 0){
    for (int idx = t; idx < HIDN*32; idx += 256){
      int n = idx >> 5, k = idx & 31;
      float v;
      if (k < 16) v = W1[n*176 + k];
      else { int cc = k - 16; v = W1[n*176 + 16 + 2*cc] + W1[n*176 + 17 + 2*cc]; }
      w1eff[idx] = v;
    }
    for (int idx = t; idx < HIDN*CHN; idx += 256){
      int n = idx >> 4, cc = idx & 15;
      w2t[idx] = W2[cc*HIDN + n];
    }
  }
  if (t < HIDN){
    float s = b1[t];
    const float* wrow = W1 + t*176 + 48;
    const float* wb = w + b*WD;
    #pragma unroll 8
    for (int k = 0; k < WD; ++k) s = fmaf(wrow[k], wb[k], s);
    c1[b*HIDN + t] = s;
  }
}

// straight-line perception for pixel at tile-row R (named-array outputs keep
// everything SROA-able -- no address-taken locals, R21-proven code shape)
#define LD4(R,dr,dc,k4) (*(const float4*)(sm + (((R)+(dr))*SWW + (c+(dc)))*20 + (k4)*4))
#define PERCEIVE(R, XC, XP, PP)                                            \
  {                                                                        \
    _Pragma("unroll")                                                      \
    for (int k4 = 0; k4 < 4; ++k4){                                        \
      XC[k4] = LD4(R,1,1,k4);                                              \
      XP[2*k4]   = (v2f){XC[k4].x, XC[k4].y};                              \
      XP[2*k4+1] = (v2f){XC[k4].z, XC[k4].w};                              \
    }                                                                      \
    _Pragma("unroll")                                                      \
    for (int k4 = 0; k4 < 2; ++k4){      /* sx -> ch 0..7 */               \
      float4 a = LD4(R,0,2,k4), b0 = LD4(R,0,0,k4);                        \
      float4 d = LD4(R,1,2,k4), e = LD4(R,1,0,k4);                         \
      float4 f = LD4(R,2,2,k4), g = LD4(R,2,0,k4);                         \
      v2f a0 = (v2f){a.x,a.y}, a1 = (v2f){a.z,a.w};                        \
      v2f b0v= (v2f){b0.x,b0.y},b1v= (v2f){b0.z,b0.w};                     \
      v2f d0 = (v2f){d.x,d.y}, d1 = (v2f){d.z,d.w};                        \
      v2f e0 = (v2f){e.x,e.y}, e1 = (v2f){e.z,e.w};                        \
      v2f f0 = (v2f){f.x,f.y}, f1 = (v2f){f.z,f.w};                        \
      v2f g0 = (v2f){g.x,g.y}, g1 = (v2f){g.z,g.w};                        \
      PP[2*k4]   = (a0-b0v) + two*(d0-e0) + (f0-g0);                       \
      PP[2*k4+1] = (a1-b1v) + two*(d1-e1) + (f1-g1);                       \
    }                                                                      \
    _Pragma("unroll")                                                      \
    for (int k4 = 2; k4 < 4; ++k4){      /* sy -> ch 8..15 */              \
      float4 a = LD4(R,2,0,k4), b0 = LD4(R,0,0,k4);                        \
      float4 d = LD4(R,2,1,k4), e = LD4(R,0,1,k4);                         \
      float4 f = LD4(R,2,2,k4), g = LD4(R,0,2,k4);                         \
      v2f a0 = (v2f){a.x,a.y}, a1 = (v2f){a.z,a.w};                        \
      v2f b0v= (v2f){b0.x,b0.y},b1v= (v2f){b0.z,b0.w};                     \
      v2f d0 = (v2f){d.x,d.y}, d1 = (v2f){d.z,d.w};                        \
      v2f e0 = (v2f){e.x,e.y}, e1 = (v2f){e.z,e.w};                        \
      v2f f0 = (v2f){f.x,f.y}, f1 = (v2f){f.z,f.w};                        \
      v2f g0 = (v2f){g.x,g.y}, g1 = (v2f){g.z,g.w};                        \
      PP[2*k4]   = (a0-b0v) + two*(d0-e0) + (f0-g0);                       \
      PP[2*k4+1] = (a1-b1v) + two*(d1-e1) + (f1-g1);                       \
    }                                                                      \
  }

// One NCA step. Block = 16x8 pixel tile x 4 hidden quarters (256 thr, q=wave,
// 2 pixels per lane: rows rA and rA+4).
// FIRST: X = input x (NCHW). Else: X = Yp*(Mp & living(Yp alpha)), Yp NHWC.
template<bool FIRST>
__global__ __launch_bounds__(NT, 3) void nca_step(
    const float* __restrict__ Xin,          // x (NCHW) if FIRST, else Y_{s-1} (NHWC)
    const unsigned char* __restrict__ Mp,   // M_{s-1} (ignored if FIRST)
    const float* __restrict__ w1eff, const float* __restrict__ w2t,
    const float* __restrict__ c1,
    uint32_t key0, uint32_t key1,
    float* __restrict__ Yn, unsigned char* __restrict__ Mn)  // Yn NHWC
{
  // monolithic carve: [xs 3600f][w1s 2048f]; red2[2][16][128] (4096f) aliases
  // the front (xs + w1s head) -- both dead after the MLP.
  __shared__ __align__(16) float sm[XS_F + W1S_F];   // 22592 B
  __shared__ float ya[STH+4][STW+4];    //   960 B: Y alpha + halo 2 (12x20)
  __shared__ float lifes[SHW][SWW];     //   720 B
  __shared__ float ufs[128];            //   512 B
  // total ~24.8 KB -> 3 blocks/CU, 576 blocks all-resident (one round)

  float* w1s = sm + XS_F;
  #define RED2(bk,ch,p) sm[(((bk)*16+(ch))*128)+(p)]

  const int T = blockIdx.x;
  const int b = T & 7;                  // image == XCD (%8 round-robin heuristic)
  const int t = T >> 3;
  const int tw0 = (t % S_TILES_X)*STW, th0 = (t / S_TILES_X)*STH;
  const int tid = threadIdx.x;

  // ---- stage upper half of w1eff (units 64..127) -> LDS (2 float4/thread)
  {
    const float4* src = (const float4*)(w1eff + 64*32);
    float4* dst = (float4*)w1s;
    dst[tid]      = src[tid];
    dst[tid + NT] = src[tid + NT];
  }

  if (FIRST){
    // one-time: scalar stage from NCHW x into NHWC LDS
    for (int idx = tid; idx < CHN*SHW*SWW; idx += NT){
      int ch = idx / (SHW*SWW), rem = idx % (SHW*SWW);
      int hh = rem / SWW, ww = rem % SWW;
      int g2 = th0 - 1 + hh, w2 = tw0 - 1 + ww;
      float v = 0.f;
      if ((unsigned)g2 < NH && (unsigned)w2 < NW)
        v = Xin[((b*CHN + ch)*NH + g2)*NW + w2];
      sm[(hh*SWW + ww)*20 + ch] = v;
    }
  } else {
    // Y alpha + halo 2 (zero-pad OOB: 0 <= 0.1 never flips the mask)
    if (tid < (STH+4)*(STW+4)){         // 240
      int hh = tid / (STW+4), ww = tid % (STW+4);
      int g2 = th0 - 2 + hh, w2 = tw0 - 2 + ww;
      float v = 0.f;
      if ((unsigned)g2 < NH && (unsigned)w2 < NW)
        v = Xin[(size_t)(b*PLANE + g2*NW + w2)*CHN + 3];
      ya[hh][ww] = v;
    }
    // coalesced float4 staging of Y tile+halo1 into regs
    float4 xr[3];
    #pragma unroll
    for (int i = 0; i < 3; ++i){
      int idx = tid + i*NT;
      float4 v = make_float4(0.f,0.f,0.f,0.f);
      if (idx < S_NF4){
        int hh = idx / (SWW*4);
        int rem = idx % (SWW*4);
        int ww = rem >> 2, k4 = rem & 3;
        int g2 = th0 - 1 + hh, w2 = tw0 - 1 + ww;
        if ((unsigned)g2 < NH && (unsigned)w2 < NW)
          v = *(const float4*)(Xin + (size_t)(b*PLANE + g2*NW + w2)*CHN + k4*4);
      }
      xr[i] = v;
    }
    __syncthreads();                    // ya visible
    if (tid < SHW*SWW){                 // life over tile + halo 1 (180 elems)
      int hh = tid / SWW, ww = tid % SWW;
      int g2 = th0 - 1 + hh, w2 = tw0 - 1 + ww;
      float lf = 0.f;
      if ((unsigned)g2 < NH && (unsigned)w2 < NW){
        float mx = ya[hh][ww];
        #pragma unroll
        for (int dr = 0; dr < 3; ++dr)
          #pragma unroll
          for (int dc = 0; dc < 3; ++dc)
            mx = fmaxf(mx, ya[hh+dr][ww+dc]);
        lf = (Mp[b*PLANE + g2*NW + w2] && (mx > 0.1f)) ? 1.f : 0.f;
      }
      lifes[hh][ww] = lf;
    }
    __syncthreads();                    // lifes visible
    #pragma unroll
    for (int i = 0; i < 3; ++i){
      int idx = tid + i*NT;
      if (idx < S_NF4){
        int hh = idx / (SWW*4);
        int rem = idx % (SWW*4);
        int ww = rem >> 2, k4 = rem & 3;
        float lf = lifes[hh][ww];
        float4 v = xr[i];
        v.x *= lf; v.y *= lf; v.z *= lf; v.w *= lf;
        *(float4*)(sm + (hh*SWW + ww)*20 + k4*4) = v;  // 16B-aligned (80B rows)
      }
    }
  }
  __syncthreads();

  const int px = tid & 63;          // lane pixel index (pixel A)
  const int q  = tid >> 6;          // hidden quarter == wave id (0..3)
  const int c = px & 15, rA = px >> 4;  // rA in 0..3; pixel B at row rA+4
  const int rB = rA + 4;
  const int gw = tw0 + c;
  const int posA = b*PLANE + (th0 + rA)*NW + gw;
  const int posB = posA + 4*NW;

  const v2f two = (v2f){2.f, 2.f};
  float4 xcA[4], xcB[4];
  v2f xpa[8], ppa[8], xpb[8], ppb[8];
  PERCEIVE(rA, xcA, xpa, ppa)
  PERCEIVE(rB, xcB, xpb, ppb)

  // threefry deduped to wave 0 (both px); M (pre_life of masked X alpha) wave 1
  if (q == 0){
    uint32_t o0, o1;
    threefry2x32(key0, key1, 0u, (uint32_t)posA, o0, o1);
    ufs[px]    = ((((o0 ^ o1) >> 31) == 0u) && (xcA[0].w > 0.1f)) ? 1.f : 0.f;
    threefry2x32(key0, key1, 0u, (uint32_t)posB, o0, o1);
    ufs[px+64] = ((((o0 ^ o1) >> 31) == 0u) && (xcB[0].w > 0.1f)) ? 1.f : 0.f;
  } else if (q == 1){
    float mxA = sm[(rA*SWW + c)*20 + 3];
    float mxB = sm[(rB*SWW + c)*20 + 3];
    #pragma unroll
    for (int dr = 0; dr < 3; ++dr)
      #pragma unroll
      for (int dc = 0; dc < 3; ++dc){
        mxA = fmaxf(mxA, sm[((rA+dr)*SWW + (c+dc))*20 + 3]);
        mxB = fmaxf(mxB, sm[((rB+dr)*SWW + (c+dc))*20 + 3]);
      }
    Mn[posA] = (mxA > 0.1f) ? (unsigned char)1 : (unsigned char)0;
    Mn[posB] = (mxB > 0.1f) ? (unsigned char)1 : (unsigned char)0;
  }

  // extract this wave's epilogue bases NOW (wave-uniform scalar select) so
  // xcA/xcB die before the MLP
  const int qq = __builtin_amdgcn_readfirstlane(q);
  float4 myxA = xcA[0], myxB = xcB[0];
  if (qq == 1){ myxA = xcA[1]; myxB = xcB[1]; }
  else if (qq == 2){ myxA = xcA[2]; myxB = xcB[2]; }
  else if (qq == 3){ myxA = xcA[3]; myxB = xcB[3]; }

  // ---- packed MLP, SPLIT-PIPE weight streaming, 2 px/lane:
  //   waves 0-1 (units 0..63):  w1 rows via uniform GLOBAL reads -> s_load (K$)
  //   waves 2-3 (units 64..127): w1 rows via LDS broadcast (w1s upper half)
  // w2t + c1 via s_load for all waves. Wave-uniform branch, no divergence.
  v2f acA[8], acB[8];
  #pragma unroll
  for (int i = 0; i < 8; ++i){ acA[i] = (v2f){0.f,0.f}; acB[i] = (v2f){0.f,0.f}; }
  const int nbase = qq << 5;
  const float* c1b = c1 + b*HIDN;

  if (qq < 2){
    #pragma unroll 2
    for (int nn = 0; nn < 32; ++nn){
      const int n = nbase + nn;
      const v2f* wx = (const v2f*)(w1eff + (n << 5));   // uniform addr -> s_load
      v2f hA01 = (v2f){c1b[n], 0.f}, hA23 = (v2f){0.f, 0.f};
      v2f hB01 = (v2f){c1b[n], 0.f}, hB23 = (v2f){0.f, 0.f};
      #pragma unroll
      for (int k = 0; k < 8; ++k){
        v2f w0 = wx[k], w1v = wx[8+k];
        hA01 = __builtin_elementwise_fma(xpa[k], w0,  hA01);  // v_pk_fma_f32
        hA23 = __builtin_elementwise_fma(ppa[k], w1v, hA23);
        hB01 = __builtin_elementwise_fma(xpb[k], w0,  hB01);
        hB23 = __builtin_elementwise_fma(ppb[k], w1v, hB23);
      }
      float hvA = fmaxf((hA01.x + hA01.y) + (hA23.x + hA23.y), 0.f);
      float hvB = fmaxf((hB01.x + hB01.y) + (hB23.x + hB23.y), 0.f);
      v2f hA = (v2f){hvA, hvA}, hB = (v2f){hvB, hvB};
      const v2f* w2p = (const v2f*)(w2t + (n << 4));    // 8 channel-pairs (s_load)
      #pragma unroll
      for (int cc2 = 0; cc2 < 8; ++cc2){
        v2f wv = w2p[cc2];
        acA[cc2] = __builtin_elementwise_fma(hA, wv, acA[cc2]);
        acB[cc2] = __builtin_elementwise_fma(hB, wv, acB[cc2]);
      }
    }
  } else {
    #pragma unroll 1
    for (int nn = 0; nn < 32; ++nn){
      const int n = nbase + nn;
      const v2f* wx = (const v2f*)(w1s + ((n - 64) << 5));  // LDS broadcast
      v2f hA01 = (v2f){c1b[n], 0.f}, hA23 = (v2f){0.f, 0.f};
      v2f hB01 = (v2f){c1b[n], 0.f}, hB23 = (v2f){0.f, 0.f};
      #pragma unroll
      for (int k = 0; k < 8; ++k){
        v2f w0 = wx[k], w1v = wx[8+k];
        hA01 = __builtin_elementwise_fma(xpa[k], w0,  hA01);
        hA23 = __builtin_elementwise_fma(ppa[k], w1v, hA23);
        hB01 = __builtin_elementwise_fma(xpb[k], w0,  hB01);
        hB23 = __builtin_elementwise_fma(ppb[k], w1v, hB23);
      }
      float hvA = fmaxf((hA01.x + hA01.y) + (hA23.x + hA23.y), 0.f);
      float hvB = fmaxf((hB01.x + hB01.y) + (hB23.x + hB23.y), 0.f);
      v2f hA = (v2f){hvA, hvA}, hB = (v2f){hvB, hvB};
      const v2f* w2p = (const v2f*)(w2t + (n << 4));
      #pragma unroll
      for (int cc2 = 0; cc2 < 8; ++cc2){
        v2f wv = w2p[cc2];
        acA[cc2] = __builtin_elementwise_fma(hA, wv, acA[cc2]);
        acB[cc2] = __builtin_elementwise_fma(hB, wv, acB[cc2]);
      }
    }
  }

  // sm (xs + w1s) dead from here; red2 aliases it (barrier makes reuse safe)
  __syncthreads();

  // ---- two-phase cross-wave reduction in the sm-aliased red2 (16KB)
  // phase 1: waves 2,3 deposit partials
  if (q >= 2){
    #pragma unroll
    for (int cc2 = 0; cc2 < 8; ++cc2){
      RED2(q-2, 2*cc2  , px)    = acA[cc2].x;
      RED2(q-2, 2*cc2+1, px)    = acA[cc2].y;
      RED2(q-2, 2*cc2  , px+64) = acB[cc2].x;
      RED2(q-2, 2*cc2+1, px+64) = acB[cc2].y;
    }
  }
  __syncthreads();
  // phase 2: wave 0 folds wave 2's partials, wave 1 folds wave 3's; deposit
  if (q < 2){
    #pragma unroll
    for (int cc2 = 0; cc2 < 8; ++cc2){
      acA[cc2].x += RED2(q, 2*cc2  , px);
      acA[cc2].y += RED2(q, 2*cc2+1, px);
      acB[cc2].x += RED2(q, 2*cc2  , px+64);
      acB[cc2].y += RED2(q, 2*cc2+1, px+64);
    }
    #pragma unroll
    for (int cc2 = 0; cc2 < 8; ++cc2){
      RED2(q, 2*cc2  , px)    = acA[cc2].x;
      RED2(q, 2*cc2+1, px)    = acA[cc2].y;
      RED2(q, 2*cc2  , px+64) = acB[cc2].x;
      RED2(q, 2*cc2+1, px+64) = acB[cc2].y;
    }
  }
  __syncthreads();

  // epilogue: quarter q writes channels 4q..4q+3 as ONE float4 per pixel (NHWC)
  {
    float ufA = ufs[px], ufB = ufs[px+64];
    int ch = q << 2;
    float a0 = RED2(0, ch+0, px) + RED2(1, ch+0, px);
    float a1 = RED2(0, ch+1, px) + RED2(1, ch+1, px);
    float a2 = RED2(0, ch+2, px) + RED2(1, ch+2, px);
    float a3 = RED2(0, ch+3, px) + RED2(1, ch+3, px);
    float4 oA = make_float4(fmaf(a0, ufA, myxA.x), fmaf(a1, ufA, myxA.y),
                            fmaf(a2, ufA, myxA.z), fmaf(a3, ufA, myxA.w));
    *(float4*)(Yn + (size_t)posA*CHN + q*4) = oA;
    float b0 = RED2(0, ch+0, px+64) + RED2(1, ch+0, px+64);
    float b1v = RED2(0, ch+1, px+64) + RED2(1, ch+1, px+64);
    float b2 = RED2(0, ch+2, px+64) + RED2(1, ch+2, px+64);
    float b3 = RED2(0, ch+3, px+64) + RED2(1, ch+3, px+64);
    float4 oB = make_float4(fmaf(b0, ufB, myxB.x), fmaf(b1v, ufB, myxB.y),
                            fmaf(b2, ufB, myxB.z), fmaf(b3, ufB, myxB.w));
    *(float4*)(Yn + (size_t)posB*CHN + q*4) = oB;
  }
  #undef RED2
}

// Final: out (NCHW) = Y_63 (NHWC) * (M_63 & living(Y_63 alpha))
__global__ __launch_bounds__(256) void nca_final(
    const float* __restrict__ Yp, const unsigned char* __restrict__ Mp,
    float* __restrict__ out)
{
  __shared__ float ya[TH+4][TW+4];     // 8x20
  __shared__ float lifes[TH][TW];
  const int T = blockIdx.x;
  const int b = T & 7;
  const int t = T >> 3;
  const int tw0 = (t % TILES_X)*TW, th0 = (t / TILES_X)*TH;
  const int tid = threadIdx.x;
  if (tid < (TH+4)*(TW+4)){
    int hh = tid / (TW+4), ww = tid % (TW+4);
    int g2 = th0 - 2 + hh, w2 = tw0 - 2 + ww;
    float v = 0.f;
    if ((unsigned)g2 < NH && (unsigned)w2 < NW)
      v = Yp[(size_t)(b*PLANE + g2*NW + w2)*CHN + 3];
    ya[hh][ww] = v;
  }
  __syncthreads();
  if (tid < TH*TW){
    int i = tid >> 4, j = tid & 15;
    float mx = ya[i+2][j+2];
    #pragma unroll
    for (int dr = 0; dr < 3; ++dr)
      #pragma unroll
      for (int dc = 0; dc < 3; ++dc)
        mx = fmaxf(mx, ya[i+1+dr][j+1+dc]);
    lifes[i][j] = (Mp[b*PLANE + (th0+i)*NW + (tw0+j)] && (mx > 0.1f)) ? 1.f : 0.f;
  }
  __syncthreads();
  for (int idx = tid; idx < CHN*TH*TW; idx += 256){
    int ch = idx >> 6, p = idx & 63;
    int i = p >> 4, j = p & 15;
    int pos = b*PLANE + (th0+i)*NW + (tw0+j);
    out[((b*CHN + ch)*NH + th0 + i)*NW + tw0 + j] = Yp[(size_t)pos*CHN + ch] * lifes[i][j];
  }
}

extern "C" void kernel_launch(void* const* d_in, const int* in_sizes, int n_in,
                              void* d_out, int out_size, void* d_ws, size_t ws_size,
                              hipStream_t stream) {
  const float* x  = (const float*)d_in[0];
  const float* w  = (const float*)d_in[1];
  // d_in[2] = sobel (hard-coded), d_in[6] = steps (=64, hard-coded)
  const float* W1 = (const float*)d_in[3];
  const float* b1 = (const float*)d_in[4];
  const float* W2 = (const float*)d_in[5];
  float* out = (float*)d_out;
  char* ws = (char*)d_ws;

  size_t off = 0;
  float*    w1eff = (float*)(ws + off);    off += (size_t)HIDN*32*4;
  float*    w2t   = (float*)(ws + off);    off += (size_t)HIDN*CHN*4;
  float*    c1    = (float*)(ws + off);    off += (size_t)NB*HIDN*4;
  float*    Yb0   = (float*)(ws + off);    off += (size_t)NB*CHN*PLANE*4;  // NHWC
  float*    Yb1   = (float*)(ws + off);    off += (size_t)NB*CHN*PLANE*4;  // NHWC
  unsigned char* Mb0 = (unsigned char*)(ws + off); off += (size_t)NB*PLANE;
  unsigned char* Mb1 = (unsigned char*)(ws + off); off += (size_t)NB*PLANE;
  (void)ws_size; (void)in_sizes; (void)n_in; (void)out_size;

  // step keys are input-independent constants: compute on host, pass as args
  uint32_t k0[NSTEPS], k1[NSTEPS];
  for (int s = 0; s < NSTEPS; ++s) threefry2x32(0u, 42u, 0u, (uint32_t)s, k0[s], k1[s]);

  nca_pre<<<dim3(NB), dim3(256), 0, stream>>>(w, W1, b1, W2, w1eff, w2t, c1);

  nca_step<true><<<dim3(S_NBLK), dim3(NT), 0, stream>>>(
      x, Mb1 /*unused*/, w1eff, w2t, c1, k0[0], k1[0], Yb0, Mb0);
  for (int s = 1; s < NSTEPS; ++s){
    const float* Yp = (s & 1) ? Yb0 : Yb1;
    float*       Yn = (s & 1) ? Yb1 : Yb0;
    const unsigned char* Mq = (s & 1) ? Mb0 : Mb1;
    unsigned char*       Mn = (s & 1) ? Mb1 : Mb0;
    nca_step<false><<<dim3(S_NBLK), dim3(NT), 0, stream>>>(
        Yp, Mq, w1eff, w2t, c1, k0[s], k1[s], Yn, Mn);
  }
  // s=63 (odd) wrote Yb1/Mb1
  nca_final<<<dim3(NBLK), dim3(256), 0, stream>>>(Yb1, Mb1, out);
}

// Round 6
// 2210.586 us; speedup vs baseline: 1.0144x; 1.0144x over previous
//
#include <hip/hip_runtime.h>
#include <stdint.h>

// IntegratedNCA: 64 NCA steps. B=8, CH=16, H=W=96, HID=128, WDIM=128.
// Multi-launch (per-step kernel = the global sync). Phase B (life masking)
// fused into the NEXT step's staging: X_s = Y_{s-1} * life_{s-1} in LDS.
//
// R24 = R23 (16x8 tile, 2 px/lane, split-pipe MLP) with scratch fixed FOR REAL:
//   R22/R23 post-mortem: identical scratch signature both rounds (VGPR=84,
//   WRITE 54MB, FETCH 27MB) => not the out-param pointers; SROA/PromoteAlloca
//   bails on the ~512B of per-lane ARRAYS at this budget and leaves them in
//   scratch entirely (VGPR 84 = arrays never promoted). Fix: NO ARRAYS.
//   Every per-lane array is now named scalars (xpa0..7, ppa0..7, acA0..7,
//   xcA0..3, xr0..2) with token-pasting macros generating straight-line code.
//   Named scalars cannot be alloca'd.
//   2-px/lane amortization theory unchanged: per-wave weight stream (w1
//   s_loads waves 0-1 / LDS broadcasts waves 2-3, w2t s_loads) covers 2x
//   pixels -> per-pixel stream cost halves on both pipes; 576 blocks <= 3/CU
//   resident -> one-round steps.
// LDS: monolithic sm[] carve; red2[2][16][128] (16KB) aliases xs+w1s head
// (both dead post-MLP). Total ~24.8KB. launch_bounds(256,3) (VGPR cap 170).
// nca_final keeps the old 16x4 geometry (1152 blocks) -- untouched.
//
// PRNG: JAX threefry, jax_threefry_partitionable=True (green R2/R5-R17):
//   split: key[i]  = threefry2x32(0,42, 0, i)   (host-side, passed as args)
//   bits : bits[p] = o0^o1, (o0,o1)=threefry2x32(key, 0, p); uniform<0.5 <=> bits>>31==0

#define CHN 16
#define HIDN 128
#define WD 128
#define NB 8
#define NH 96
#define NW 96
#define NSTEPS 64
#define PLANE (NH*NW)          // 9216
#define NT 256

// ---- final-kernel tile geometry ----
#define TW 16
#define TH 4
#define TILES_X (NW/TW)        // 6
#define TILES_Y (NH/TH)        // 24
#define TPI (TILES_X*TILES_Y)  // 144
#define NBLK (NB*TPI)          // 1152

// ---- step-kernel tile geometry (16x8, 2 px/lane) ----
#define STW 16
#define STH 8
#define S_TILES_X (NW/STW)     // 6
#define S_TILES_Y (NH/STH)     // 12
#define S_TPI (S_TILES_X*S_TILES_Y) // 72
#define S_NBLK (NB*S_TPI)      // 576
#define SHW (STH+2)            // 10 staged rows (halo 1)
#define SWW (STW+2)            // 18 staged cols (halo 1)
#define S_NF4 (SHW*SWW*4)      // 720 staged float4s
#define XS_F (SHW*SWW*20)      // 3600 floats (NHWC pad 20)
#define W1S_F (64*32)          // 2048 floats (upper w1 half)

typedef float v2f __attribute__((ext_vector_type(2)));

__host__ __device__ __forceinline__ uint32_t rotl(uint32_t v, int d){ return (v<<d)|(v>>(32-d)); }

__host__ __device__ __forceinline__ void threefry2x32(uint32_t k0, uint32_t k1,
                                                      uint32_t x0, uint32_t x1,
                                                      uint32_t &o0, uint32_t &o1){
  uint32_t k2 = k0 ^ k1 ^ 0x1BD11BDAu;
  x0 += k0; x1 += k1;
  x0 += x1; x1 = rotl(x1,13); x1 ^= x0;
  x0 += x1; x1 = rotl(x1,15); x1 ^= x0;
  x0 += x1; x1 = rotl(x1,26); x1 ^= x0;
  x0 += x1; x1 = rotl(x1, 6); x1 ^= x0;
  x0 += k1; x1 += k2 + 1u;
  x0 += x1; x1 = rotl(x1,17); x1 ^= x0;
  x0 += x1; x1 = rotl(x1,29); x1 ^= x0;
  x0 += x1; x1 = rotl(x1,16); x1 ^= x0;
  x0 += x1; x1 = rotl(x1,24); x1 ^= x0;
  x0 += k2; x1 += k0 + 2u;
  x0 += x1; x1 = rotl(x1,13); x1 ^= x0;
  x0 += x1; x1 = rotl(x1,15); x1 ^= x0;
  x0 += x1; x1 = rotl(x1,26); x1 ^= x0;
  x0 += x1; x1 = rotl(x1, 6); x1 ^= x0;
  x0 += k0; x1 += k1 + 3u;
  x0 += x1; x1 = rotl(x1,17); x1 ^= x0;
  x0 += x1; x1 = rotl(x1,29); x1 ^= x0;
  x0 += x1; x1 = rotl(x1,16); x1 ^= x0;
  x0 += x1; x1 = rotl(x1,24); x1 ^= x0;
  x0 += k1; x1 += k2 + 4u;
  x0 += x1; x1 = rotl(x1,13); x1 ^= x0;
  x0 += x1; x1 = rotl(x1,15); x1 ^= x0;
  x0 += x1; x1 = rotl(x1,26); x1 ^= x0;
  x0 += x1; x1 = rotl(x1, 6); x1 ^= x0;
  x0 += k2; x1 += k0 + 5u;
  o0 = x0; o1 = x1;
}

// Pre: w1eff[128][32] natural layout (cols 0..15 = W1[:, :16]; cols 16..31 =
// folded perception pairs P[cc] = W1[:,16+2cc]+W1[:,17+2cc]) -- v2f-readable.
// w2t[128][16] = W2^T, c1[8][128] = b1 + W1[:,48:176].w[b].
__global__ __launch_bounds__(256) void nca_pre(
    const float* __restrict__ w, const float* __restrict__ W1,
    const float* __restrict__ b1, const float* __restrict__ W2,
    float* __restrict__ w1eff, float* __restrict__ w2t, float* __restrict__ c1)
{
  const int b = blockIdx.x, t = threadIdx.x;
  if (b == 0){
    for (int idx = t; idx < HIDN*32; idx += 256){
      int n = idx >> 5, k = idx & 31;
      float v;
      if (k < 16) v = W1[n*176 + k];
      else { int cc = k - 16; v = W1[n*176 + 16 + 2*cc] + W1[n*176 + 17 + 2*cc]; }
      w1eff[idx] = v;
    }
    for (int idx = t; idx < HIDN*CHN; idx += 256){
      int n = idx >> 4, cc = idx & 15;
      w2t[idx] = W2[cc*HIDN + n];
    }
  }
  if (t < HIDN){
    float s = b1[t];
    const float* wrow = W1 + t*176 + 48;
    const float* wb = w + b*WD;
    #pragma unroll 8
    for (int k = 0; k < WD; ++k) s = fmaf(wrow[k], wb[k], s);
    c1[b*HIDN + t] = s;
  }
}

// LDS tile read (floats base sm, NHWC pad-20 rows)
#define LD4(R,dr,dc,k4) (*(const float4*)(sm + (((R)+(dr))*SWW + (c+(dc)))*20 + (k4)*4))

// sobel-x pair for channels 2k4,2k4+1 / 2k4+2.. (two v2f outs per k4)
#define SXP(R,k4,P0,P1) { \
  float4 a = LD4(R,0,2,k4), b0 = LD4(R,0,0,k4); \
  float4 d = LD4(R,1,2,k4), e = LD4(R,1,0,k4); \
  float4 f = LD4(R,2,2,k4), g = LD4(R,2,0,k4); \
  P0 = ((v2f){a.x,a.y}-(v2f){b0.x,b0.y}) + two*((v2f){d.x,d.y}-(v2f){e.x,e.y}) + ((v2f){f.x,f.y}-(v2f){g.x,g.y}); \
  P1 = ((v2f){a.z,a.w}-(v2f){b0.z,b0.w}) + two*((v2f){d.z,d.w}-(v2f){e.z,e.w}) + ((v2f){f.z,f.w}-(v2f){g.z,g.w}); }

// sobel-y pair
#define SYP(R,k4,P0,P1) { \
  float4 a = LD4(R,2,0,k4), b0 = LD4(R,0,0,k4); \
  float4 d = LD4(R,2,1,k4), e = LD4(R,0,1,k4); \
  float4 f = LD4(R,2,2,k4), g = LD4(R,0,2,k4); \
  P0 = ((v2f){a.x,a.y}-(v2f){b0.x,b0.y}) + two*((v2f){d.x,d.y}-(v2f){e.x,e.y}) + ((v2f){f.x,f.y}-(v2f){g.x,g.y}); \
  P1 = ((v2f){a.z,a.w}-(v2f){b0.z,b0.w}) + two*((v2f){d.z,d.w}-(v2f){e.z,e.w}) + ((v2f){f.z,f.w}-(v2f){g.z,g.w}); }

// layer-1 fma step k (named scalars via token paste)
#define MK(k) { v2f w0 = wx[k], w1v = wx[8+k]; \
  hA01 = __builtin_elementwise_fma(xpa##k, w0,  hA01); \
  hA23 = __builtin_elementwise_fma(ppa##k, w1v, hA23); \
  hB01 = __builtin_elementwise_fma(xpb##k, w0,  hB01); \
  hB23 = __builtin_elementwise_fma(ppb##k, w1v, hB23); }

// layer-2 fma step k
#define L2K(k) { v2f wv = w2p[k]; \
  acA##k = __builtin_elementwise_fma(hAv, wv, acA##k); \
  acB##k = __builtin_elementwise_fma(hBv, wv, acB##k); }

// full per-hidden-unit body; WX = weight-row pointer expression
#define MLP_ONE_N(WX) { \
  const v2f* wx = (WX); \
  float c1n = c1b[n]; \
  v2f hA01 = (v2f){c1n, 0.f}, hA23 = (v2f){0.f, 0.f}; \
  v2f hB01 = (v2f){c1n, 0.f}, hB23 = (v2f){0.f, 0.f}; \
  MK(0) MK(1) MK(2) MK(3) MK(4) MK(5) MK(6) MK(7) \
  float hvA = fmaxf((hA01.x + hA01.y) + (hA23.x + hA23.y), 0.f); \
  float hvB = fmaxf((hB01.x + hB01.y) + (hB23.x + hB23.y), 0.f); \
  v2f hAv = (v2f){hvA, hvA}, hBv = (v2f){hvB, hvB}; \
  const v2f* w2p = (const v2f*)(w2t + (n << 4)); \
  L2K(0) L2K(1) L2K(2) L2K(3) L2K(4) L2K(5) L2K(6) L2K(7) }

// reduction deposit / fold (named acc scalars)
#define DEP2(k) { RED2(q-2,2*k,px)=acA##k.x; RED2(q-2,2*k+1,px)=acA##k.y; \
                  RED2(q-2,2*k,px+64)=acB##k.x; RED2(q-2,2*k+1,px+64)=acB##k.y; }
#define FOLD2(k) { acA##k.x += RED2(q,2*k,px);    acA##k.y += RED2(q,2*k+1,px); \
                   acB##k.x += RED2(q,2*k,px+64); acB##k.y += RED2(q,2*k+1,px+64); }
#define DEPW(k) { RED2(q,2*k,px)=acA##k.x; RED2(q,2*k+1,px)=acA##k.y; \
                  RED2(q,2*k,px+64)=acB##k.x; RED2(q,2*k+1,px+64)=acB##k.y; }

// One NCA step. Block = 16x8 pixel tile x 4 hidden quarters (256 thr, q=wave,
// 2 pixels per lane: rows rA and rA+4).
// FIRST: X = input x (NCHW). Else: X = Yp*(Mp & living(Yp alpha)), Yp NHWC.
template<bool FIRST>
__global__ __launch_bounds__(NT, 3) void nca_step(
    const float* __restrict__ Xin,          // x (NCHW) if FIRST, else Y_{s-1} (NHWC)
    const unsigned char* __restrict__ Mp,   // M_{s-1} (ignored if FIRST)
    const float* __restrict__ w1eff, const float* __restrict__ w2t,
    const float* __restrict__ c1,
    uint32_t key0, uint32_t key1,
    float* __restrict__ Yn, unsigned char* __restrict__ Mn)  // Yn NHWC
{
  // monolithic carve: [xs 3600f][w1s 2048f]; red2[2][16][128] (4096f) aliases
  // the front (xs + w1s head) -- both dead after the MLP.
  __shared__ __align__(16) float sm[XS_F + W1S_F];   // 22592 B
  __shared__ float ya[STH+4][STW+4];    //   960 B: Y alpha + halo 2 (12x20)
  __shared__ float lifes[SHW][SWW];     //   720 B
  __shared__ float ufs[128];            //   512 B
  // total ~24.8 KB -> 3 blocks/CU, 576 blocks all-resident (one round)

  float* w1s = sm + XS_F;
  #define RED2(bk,ch,p) sm[(((bk)*16+(ch))*128)+(p)]

  const int T = blockIdx.x;
  const int b = T & 7;                  // image == XCD (%8 round-robin heuristic)
  const int t = T >> 3;
  const int tw0 = (t % S_TILES_X)*STW, th0 = (t / S_TILES_X)*STH;
  const int tid = threadIdx.x;

  // ---- stage upper half of w1eff (units 64..127) -> LDS (2 float4/thread)
  {
    const float4* src = (const float4*)(w1eff + 64*32);
    float4* dst = (float4*)w1s;
    dst[tid]      = src[tid];
    dst[tid + NT] = src[tid + NT];
  }

  if (FIRST){
    // one-time: scalar stage from NCHW x into NHWC LDS
    for (int idx = tid; idx < CHN*SHW*SWW; idx += NT){
      int ch = idx / (SHW*SWW), rem = idx % (SHW*SWW);
      int hh = rem / SWW, ww = rem % SWW;
      int g2 = th0 - 1 + hh, w2 = tw0 - 1 + ww;
      float v = 0.f;
      if ((unsigned)g2 < NH && (unsigned)w2 < NW)
        v = Xin[((b*CHN + ch)*NH + g2)*NW + w2];
      sm[(hh*SWW + ww)*20 + ch] = v;
    }
    __syncthreads();
  } else {
    // Y alpha + halo 2 (zero-pad OOB: 0 <= 0.1 never flips the mask)
    if (tid < (STH+4)*(STW+4)){         // 240
      int hh = tid / (STW+4), ww = tid % (STW+4);
      int g2 = th0 - 2 + hh, w2 = tw0 - 2 + ww;
      float v = 0.f;
      if ((unsigned)g2 < NH && (unsigned)w2 < NW)
        v = Xin[(size_t)(b*PLANE + g2*NW + w2)*CHN + 3];
      ya[hh][ww] = v;
    }
    // coalesced float4 staging of Y tile+halo1 into NAMED regs
    // idx0=tid (<720 always), idx1=tid+256 (<720 always), idx2=tid+512 (guard)
    float4 xr0 = make_float4(0.f,0.f,0.f,0.f), xr1 = xr0, xr2 = xr0;
    #define STAGE_LD(XR, IDX, GUARD) { \
      int idx = (IDX); \
      if (!(GUARD) || idx < S_NF4){ \
        int hh = idx / (SWW*4); int rem = idx % (SWW*4); \
        int ww = rem >> 2, k4 = rem & 3; \
        int g2 = th0 - 1 + hh, w2 = tw0 - 1 + ww; \
        if ((unsigned)g2 < NH && (unsigned)w2 < NW) \
          XR = *(const float4*)(Xin + (size_t)(b*PLANE + g2*NW + w2)*CHN + k4*4); \
      } }
    STAGE_LD(xr0, tid,        0)
    STAGE_LD(xr1, tid + NT,   0)
    STAGE_LD(xr2, tid + 2*NT, 1)
    __syncthreads();                    // ya visible
    if (tid < SHW*SWW){                 // life over tile + halo 1 (180 elems)
      int hh = tid / SWW, ww = tid % SWW;
      int g2 = th0 - 1 + hh, w2 = tw0 - 1 + ww;
      float lf = 0.f;
      if ((unsigned)g2 < NH && (unsigned)w2 < NW){
        float mx = ya[hh][ww];
        #pragma unroll
        for (int dr = 0; dr < 3; ++dr)
          #pragma unroll
          for (int dc = 0; dc < 3; ++dc)
            mx = fmaxf(mx, ya[hh+dr][ww+dc]);
        lf = (Mp[b*PLANE + g2*NW + w2] && (mx > 0.1f)) ? 1.f : 0.f;
      }
      lifes[hh][ww] = lf;
    }
    __syncthreads();                    // lifes visible
    #define STAGE_ST(XR, IDX, GUARD) { \
      int idx = (IDX); \
      if (!(GUARD) || idx < S_NF4){ \
        int hh = idx / (SWW*4); int rem = idx % (SWW*4); \
        int ww = rem >> 2, k4 = rem & 3; \
        float lf = lifes[hh][ww]; \
        float4 v = XR; \
        v.x *= lf; v.y *= lf; v.z *= lf; v.w *= lf; \
        *(float4*)(sm + (hh*SWW + ww)*20 + k4*4) = v; \
      } }
    STAGE_ST(xr0, tid,        0)
    STAGE_ST(xr1, tid + NT,   0)
    STAGE_ST(xr2, tid + 2*NT, 1)
    __syncthreads();
  }

  const int px = tid & 63;          // lane pixel index (pixel A)
  const int q  = tid >> 6;          // hidden quarter == wave id (0..3)
  const int c = px & 15, rA = px >> 4;  // rA in 0..3; pixel B at row rA+4
  const int rB = rA + 4;
  const int gw = tw0 + c;
  const int posA = b*PLANE + (th0 + rA)*NW + gw;
  const int posB = posA + 4*NW;

  const v2f two = (v2f){2.f, 2.f};

  // ---- perception, all named scalars (no allocas anywhere)
  float4 xcA0 = LD4(rA,1,1,0), xcA1 = LD4(rA,1,1,1), xcA2 = LD4(rA,1,1,2), xcA3 = LD4(rA,1,1,3);
  float4 xcB0 = LD4(rB,1,1,0), xcB1 = LD4(rB,1,1,1), xcB2 = LD4(rB,1,1,2), xcB3 = LD4(rB,1,1,3);
  v2f xpa0 = (v2f){xcA0.x,xcA0.y}, xpa1 = (v2f){xcA0.z,xcA0.w};
  v2f xpa2 = (v2f){xcA1.x,xcA1.y}, xpa3 = (v2f){xcA1.z,xcA1.w};
  v2f xpa4 = (v2f){xcA2.x,xcA2.y}, xpa5 = (v2f){xcA2.z,xcA2.w};
  v2f xpa6 = (v2f){xcA3.x,xcA3.y}, xpa7 = (v2f){xcA3.z,xcA3.w};
  v2f xpb0 = (v2f){xcB0.x,xcB0.y}, xpb1 = (v2f){xcB0.z,xcB0.w};
  v2f xpb2 = (v2f){xcB1.x,xcB1.y}, xpb3 = (v2f){xcB1.z,xcB1.w};
  v2f xpb4 = (v2f){xcB2.x,xcB2.y}, xpb5 = (v2f){xcB2.z,xcB2.w};
  v2f xpb6 = (v2f){xcB3.x,xcB3.y}, xpb7 = (v2f){xcB3.z,xcB3.w};
  v2f ppa0, ppa1, ppa2, ppa3, ppa4, ppa5, ppa6, ppa7;
  v2f ppb0, ppb1, ppb2, ppb3, ppb4, ppb5, ppb6, ppb7;
  SXP(rA,0,ppa0,ppa1) SXP(rA,1,ppa2,ppa3) SYP(rA,2,ppa4,ppa5) SYP(rA,3,ppa6,ppa7)
  SXP(rB,0,ppb0,ppb1) SXP(rB,1,ppb2,ppb3) SYP(rB,2,ppb4,ppb5) SYP(rB,3,ppb6,ppb7)

  // threefry deduped to wave 0 (both px); M (pre_life of masked X alpha) wave 1
  if (q == 0){
    uint32_t o0, o1;
    threefry2x32(key0, key1, 0u, (uint32_t)posA, o0, o1);
    ufs[px]    = ((((o0 ^ o1) >> 31) == 0u) && (xcA0.w > 0.1f)) ? 1.f : 0.f;
    threefry2x32(key0, key1, 0u, (uint32_t)posB, o0, o1);
    ufs[px+64] = ((((o0 ^ o1) >> 31) == 0u) && (xcB0.w > 0.1f)) ? 1.f : 0.f;
  } else if (q == 1){
    float mxA = sm[(rA*SWW + c)*20 + 3];
    float mxB = sm[(rB*SWW + c)*20 + 3];
    #pragma unroll
    for (int dr = 0; dr < 3; ++dr)
      #pragma unroll
      for (int dc = 0; dc < 3; ++dc){
        mxA = fmaxf(mxA, sm[((rA+dr)*SWW + (c+dc))*20 + 3]);
        mxB = fmaxf(mxB, sm[((rB+dr)*SWW + (c+dc))*20 + 3]);
      }
    Mn[posA] = (mxA > 0.1f) ? (unsigned char)1 : (unsigned char)0;
    Mn[posB] = (mxB > 0.1f) ? (unsigned char)1 : (unsigned char)0;
  }

  // extract this wave's epilogue bases NOW (wave-uniform scalar select) so
  // the xc scalars die before the MLP
  const int qq = __builtin_amdgcn_readfirstlane(q);
  float4 myxA = xcA0, myxB = xcB0;
  if (qq == 1){ myxA = xcA1; myxB = xcB1; }
  else if (qq == 2){ myxA = xcA2; myxB = xcB2; }
  else if (qq == 3){ myxA = xcA3; myxB = xcB3; }

  // ---- packed MLP, SPLIT-PIPE weight streaming, 2 px/lane:
  //   waves 0-1 (units 0..63):  w1 rows via uniform GLOBAL reads -> s_load (K$)
  //   waves 2-3 (units 64..127): w1 rows via LDS broadcast (w1s upper half)
  // w2t + c1 via s_load for all waves. Wave-uniform branch, no divergence.
  v2f acA0 = (v2f){0.f,0.f}, acA1 = acA0, acA2 = acA0, acA3 = acA0,
      acA4 = acA0, acA5 = acA0, acA6 = acA0, acA7 = acA0;
  v2f acB0 = acA0, acB1 = acA0, acB2 = acA0, acB3 = acA0,
      acB4 = acA0, acB5 = acA0, acB6 = acA0, acB7 = acA0;
  const int nbase = qq << 5;
  const float* c1b = c1 + b*HIDN;

  if (qq < 2){
    #pragma unroll 2
    for (int nn = 0; nn < 32; ++nn){
      const int n = nbase + nn;
      MLP_ONE_N((const v2f*)(w1eff + (n << 5)))   // uniform addr -> s_load
    }
  } else {
    #pragma unroll 1
    for (int nn = 0; nn < 32; ++nn){
      const int n = nbase + nn;
      MLP_ONE_N((const v2f*)(w1s + ((n - 64) << 5)))  // LDS broadcast
    }
  }

  // sm (xs + w1s) dead from here; red2 aliases it (barrier makes reuse safe)
  __syncthreads();

  // ---- two-phase cross-wave reduction in the sm-aliased red2 (16KB)
  // phase 1: waves 2,3 deposit partials
  if (q >= 2){
    DEP2(0) DEP2(1) DEP2(2) DEP2(3) DEP2(4) DEP2(5) DEP2(6) DEP2(7)
  }
  __syncthreads();
  // phase 2: wave 0 folds wave 2's partials, wave 1 folds wave 3's; deposit
  if (q < 2){
    FOLD2(0) FOLD2(1) FOLD2(2) FOLD2(3) FOLD2(4) FOLD2(5) FOLD2(6) FOLD2(7)
    DEPW(0) DEPW(1) DEPW(2) DEPW(3) DEPW(4) DEPW(5) DEPW(6) DEPW(7)
  }
  __syncthreads();

  // epilogue: quarter q writes channels 4q..4q+3 as ONE float4 per pixel (NHWC)
  {
    float ufA = ufs[px], ufB = ufs[px+64];
    int ch = q << 2;
    float a0 = RED2(0, ch+0, px) + RED2(1, ch+0, px);
    float a1 = RED2(0, ch+1, px) + RED2(1, ch+1, px);
    float a2 = RED2(0, ch+2, px) + RED2(1, ch+2, px);
    float a3 = RED2(0, ch+3, px) + RED2(1, ch+3, px);
    float4 oA = make_float4(fmaf(a0, ufA, myxA.x), fmaf(a1, ufA, myxA.y),
                            fmaf(a2, ufA, myxA.z), fmaf(a3, ufA, myxA.w));
    *(float4*)(Yn + (size_t)posA*CHN + q*4) = oA;
    float b0 = RED2(0, ch+0, px+64) + RED2(1, ch+0, px+64);
    float b1v = RED2(0, ch+1, px+64) + RED2(1, ch+1, px+64);
    float b2 = RED2(0, ch+2, px+64) + RED2(1, ch+2, px+64);
    float b3 = RED2(0, ch+3, px+64) + RED2(1, ch+3, px+64);
    float4 oB = make_float4(fmaf(b0, ufB, myxB.x), fmaf(b1v, ufB, myxB.y),
                            fmaf(b2, ufB, myxB.z), fmaf(b3, ufB, myxB.w));
    *(float4*)(Yn + (size_t)posB*CHN + q*4) = oB;
  }
  #undef RED2
}

// Final: out (NCHW) = Y_63 (NHWC) * (M_63 & living(Y_63 alpha))
__global__ __launch_bounds__(256) void nca_final(
    const float* __restrict__ Yp, const unsigned char* __restrict__ Mp,
    float* __restrict__ out)
{
  __shared__ float ya[TH+4][TW+4];     // 8x20
  __shared__ float lifes[TH][TW];
  const int T = blockIdx.x;
  const int b = T & 7;
  const int t = T >> 3;
  const int tw0 = (t % TILES_X)*TW, th0 = (t / TILES_X)*TH;
  const int tid = threadIdx.x;
  if (tid < (TH+4)*(TW+4)){
    int hh = tid / (TW+4), ww = tid % (TW+4);
    int g2 = th0 - 2 + hh, w2 = tw0 - 2 + ww;
    float v = 0.f;
    if ((unsigned)g2 < NH && (unsigned)w2 < NW)
      v = Yp[(size_t)(b*PLANE + g2*NW + w2)*CHN + 3];
    ya[hh][ww] = v;
  }
  __syncthreads();
  if (tid < TH*TW){
    int i = tid >> 4, j = tid & 15;
    float mx = ya[i+2][j+2];
    #pragma unroll
    for (int dr = 0; dr < 3; ++dr)
      #pragma unroll
      for (int dc = 0; dc < 3; ++dc)
        mx = fmaxf(mx, ya[i+1+dr][j+1+dc]);
    lifes[i][j] = (Mp[b*PLANE + (th0+i)*NW + (tw0+j)] && (mx > 0.1f)) ? 1.f : 0.f;
  }
  __syncthreads();
  for (int idx = tid; idx < CHN*TH*TW; idx += 256){
    int ch = idx >> 6, p = idx & 63;
    int i = p >> 4, j = p & 15;
    int pos = b*PLANE + (th0+i)*NW + (tw0+j);
    out[((b*CHN + ch)*NH + th0 + i)*NW + tw0 + j] = Yp[(size_t)pos*CHN + ch] * lifes[i][j];
  }
}

extern "C" void kernel_launch(void* const* d_in, const int* in_sizes, int n_in,
                              void* d_out, int out_size, void* d_ws, size_t ws_size,
                              hipStream_t stream) {
  const float* x  = (const float*)d_in[0];
  const float* w  = (const float*)d_in[1];
  // d_in[2] = sobel (hard-coded), d_in[6] = steps (=64, hard-coded)
  const float* W1 = (const float*)d_in[3];
  const float* b1 = (const float*)d_in[4];
  const float* W2 = (const float*)d_in[5];
  float* out = (float*)d_out;
  char* ws = (char*)d_ws;

  size_t off = 0;
  float*    w1eff = (float*)(ws + off);    off += (size_t)HIDN*32*4;
  float*    w2t   = (float*)(ws + off);    off += (size_t)HIDN*CHN*4;
  float*    c1    = (float*)(ws + off);    off += (size_t)NB*HIDN*4;
  float*    Yb0   = (float*)(ws + off);    off += (size_t)NB*CHN*PLANE*4;  // NHWC
  float*    Yb1   = (float*)(ws + off);    off += (size_t)NB*CHN*PLANE*4;  // NHWC
  unsigned char* Mb0 = (unsigned char*)(ws + off); off += (size_t)NB*PLANE;
  unsigned char* Mb1 = (unsigned char*)(ws + off); off += (size_t)NB*PLANE;
  (void)ws_size; (void)in_sizes; (void)n_in; (void)out_size;

  // step keys are input-independent constants: compute on host, pass as args
  uint32_t k0[NSTEPS], k1[NSTEPS];
  for (int s = 0; s < NSTEPS; ++s) threefry2x32(0u, 42u, 0u, (uint32_t)s, k0[s], k1[s]);

  nca_pre<<<dim3(NB), dim3(256), 0, stream>>>(w, W1, b1, W2, w1eff, w2t, c1);

  nca_step<true><<<dim3(S_NBLK), dim3(NT), 0, stream>>>(
      x, Mb1 /*unused*/, w1eff, w2t, c1, k0[0], k1[0], Yb0, Mb0);
  for (int s = 1; s < NSTEPS; ++s){
    const float* Yp = (s & 1) ? Yb0 : Yb1;
    float*       Yn = (s & 1) ? Yb1 : Yb0;
    const unsigned char* Mq = (s & 1) ? Mb0 : Mb1;
    unsigned char*       Mn = (s & 1) ? Mb1 : Mb0;
    nca_step<false><<<dim3(S_NBLK), dim3(NT), 0, stream>>>(
        Yp, Mq, w1eff, w2t, c1, k0[s], k1[s], Yn, Mn);
  }
  // s=63 (odd) wrote Yb1/Mb1
  nca_final<<<dim3(NBLK), dim3(256), 0, stream>>>(Yb1, Mb1, out);
}

// Round 7
// 1568.006 us; speedup vs baseline: 1.4301x; 1.4098x over previous
//
#include <hip/hip_runtime.h>
#include <stdint.h>

// IntegratedNCA: 64 NCA steps. B=8, CH=16, H=W=96, HID=128, WDIM=128.
// Multi-launch (per-step kernel = the global sync). Phase B (life masking)
// fused into the NEXT step's staging: X_s = Y_{s-1} * life_{s-1} in LDS.
//
// R25 = R24 (named-scalar 16x8 / 2 px/lane / split-pipe MLP) with the REAL
// spill fix: launch_bounds (256,3) -> (256,2).
//   R22/R23/R24 post-mortem: identical scratch signature (VGPR=84, WRITE
//   54MB, FETCH 27MB) across array, macro-array, and pure-named-scalar
//   versions => not SROA/alloca. Cause: live-set arithmetic. 2 px/lane needs
//   ~190-200 VGPR (xp/pp 128 + acc 32 + myx/temps ~35) vs the (256,3) cap of
//   170 -> RA catastrophically spills ~90 regs (366B/thread = the 54MB).
//   Fix: cap 256 via (256,2). Trade: 2 blocks/CU (512/576 resident, 12.5%
//   tail, 8 waves/CU). Amortization math survives: per-CU broadcast stream
//   halves vs R21 (8 waves x 10KB vs 16 x 10KB for the same 288 px/CU).
// LDS: monolithic sm[] carve; red2[2][16][128] (16KB) aliases xs+w1s head
// (both dead post-MLP). Total ~24.8KB.
// nca_final keeps the old 16x4 geometry (1152 blocks) -- untouched.
//
// PRNG: JAX threefry, jax_threefry_partitionable=True (green R2/R5-R17):
//   split: key[i]  = threefry2x32(0,42, 0, i)   (host-side, passed as args)
//   bits : bits[p] = o0^o1, (o0,o1)=threefry2x32(key, 0, p); uniform<0.5 <=> bits>>31==0

#define CHN 16
#define HIDN 128
#define WD 128
#define NB 8
#define NH 96
#define NW 96
#define NSTEPS 64
#define PLANE (NH*NW)          // 9216
#define NT 256

// ---- final-kernel tile geometry ----
#define TW 16
#define TH 4
#define TILES_X (NW/TW)        // 6
#define TILES_Y (NH/TH)        // 24
#define TPI (TILES_X*TILES_Y)  // 144
#define NBLK (NB*TPI)          // 1152

// ---- step-kernel tile geometry (16x8, 2 px/lane) ----
#define STW 16
#define STH 8
#define S_TILES_X (NW/STW)     // 6
#define S_TILES_Y (NH/STH)     // 12
#define S_TPI (S_TILES_X*S_TILES_Y) // 72
#define S_NBLK (NB*S_TPI)      // 576
#define SHW (STH+2)            // 10 staged rows (halo 1)
#define SWW (STW+2)            // 18 staged cols (halo 1)
#define S_NF4 (SHW*SWW*4)      // 720 staged float4s
#define XS_F (SHW*SWW*20)      // 3600 floats (NHWC pad 20)
#define W1S_F (64*32)          // 2048 floats (upper w1 half)

typedef float v2f __attribute__((ext_vector_type(2)));

__host__ __device__ __forceinline__ uint32_t rotl(uint32_t v, int d){ return (v<<d)|(v>>(32-d)); }

__host__ __device__ __forceinline__ void threefry2x32(uint32_t k0, uint32_t k1,
                                                      uint32_t x0, uint32_t x1,
                                                      uint32_t &o0, uint32_t &o1){
  uint32_t k2 = k0 ^ k1 ^ 0x1BD11BDAu;
  x0 += k0; x1 += k1;
  x0 += x1; x1 = rotl(x1,13); x1 ^= x0;
  x0 += x1; x1 = rotl(x1,15); x1 ^= x0;
  x0 += x1; x1 = rotl(x1,26); x1 ^= x0;
  x0 += x1; x1 = rotl(x1, 6); x1 ^= x0;
  x0 += k1; x1 += k2 + 1u;
  x0 += x1; x1 = rotl(x1,17); x1 ^= x0;
  x0 += x1; x1 = rotl(x1,29); x1 ^= x0;
  x0 += x1; x1 = rotl(x1,16); x1 ^= x0;
  x0 += x1; x1 = rotl(x1,24); x1 ^= x0;
  x0 += k2; x1 += k0 + 2u;
  x0 += x1; x1 = rotl(x1,13); x1 ^= x0;
  x0 += x1; x1 = rotl(x1,15); x1 ^= x0;
  x0 += x1; x1 = rotl(x1,26); x1 ^= x0;
  x0 += x1; x1 = rotl(x1, 6); x1 ^= x0;
  x0 += k0; x1 += k1 + 3u;
  x0 += x1; x1 = rotl(x1,17); x1 ^= x0;
  x0 += x1; x1 = rotl(x1,29); x1 ^= x0;
  x0 += x1; x1 = rotl(x1,16); x1 ^= x0;
  x0 += x1; x1 = rotl(x1,24); x1 ^= x0;
  x0 += k1; x1 += k2 + 4u;
  x0 += x1; x1 = rotl(x1,13); x1 ^= x0;
  x0 += x1; x1 = rotl(x1,15); x1 ^= x0;
  x0 += x1; x1 = rotl(x1,26); x1 ^= x0;
  x0 += x1; x1 = rotl(x1, 6); x1 ^= x0;
  x0 += k2; x1 += k0 + 5u;
  o0 = x0; o1 = x1;
}

// Pre: w1eff[128][32] natural layout (cols 0..15 = W1[:, :16]; cols 16..31 =
// folded perception pairs P[cc] = W1[:,16+2cc]+W1[:,17+2cc]) -- v2f-readable.
// w2t[128][16] = W2^T, c1[8][128] = b1 + W1[:,48:176].w[b].
__global__ __launch_bounds__(256) void nca_pre(
    const float* __restrict__ w, const float* __restrict__ W1,
    const float* __restrict__ b1, const float* __restrict__ W2,
    float* __restrict__ w1eff, float* __restrict__ w2t, float* __restrict__ c1)
{
  const int b = blockIdx.x, t = threadIdx.x;
  if (b == 0){
    for (int idx = t; idx < HIDN*32; idx += 256){
      int n = idx >> 5, k = idx & 31;
      float v;
      if (k < 16) v = W1[n*176 + k];
      else { int cc = k - 16; v = W1[n*176 + 16 + 2*cc] + W1[n*176 + 17 + 2*cc]; }
      w1eff[idx] = v;
    }
    for (int idx = t; idx < HIDN*CHN; idx += 256){
      int n = idx >> 4, cc = idx & 15;
      w2t[idx] = W2[cc*HIDN + n];
    }
  }
  if (t < HIDN){
    float s = b1[t];
    const float* wrow = W1 + t*176 + 48;
    const float* wb = w + b*WD;
    #pragma unroll 8
    for (int k = 0; k < WD; ++k) s = fmaf(wrow[k], wb[k], s);
    c1[b*HIDN + t] = s;
  }
}

// LDS tile read (floats base sm, NHWC pad-20 rows)
#define LD4(R,dr,dc,k4) (*(const float4*)(sm + (((R)+(dr))*SWW + (c+(dc)))*20 + (k4)*4))

// sobel-x pair for channels 2k4,2k4+1 / 2k4+2.. (two v2f outs per k4)
#define SXP(R,k4,P0,P1) { \
  float4 a = LD4(R,0,2,k4), b0 = LD4(R,0,0,k4); \
  float4 d = LD4(R,1,2,k4), e = LD4(R,1,0,k4); \
  float4 f = LD4(R,2,2,k4), g = LD4(R,2,0,k4); \
  P0 = ((v2f){a.x,a.y}-(v2f){b0.x,b0.y}) + two*((v2f){d.x,d.y}-(v2f){e.x,e.y}) + ((v2f){f.x,f.y}-(v2f){g.x,g.y}); \
  P1 = ((v2f){a.z,a.w}-(v2f){b0.z,b0.w}) + two*((v2f){d.z,d.w}-(v2f){e.z,e.w}) + ((v2f){f.z,f.w}-(v2f){g.z,g.w}); }

// sobel-y pair
#define SYP(R,k4,P0,P1) { \
  float4 a = LD4(R,2,0,k4), b0 = LD4(R,0,0,k4); \
  float4 d = LD4(R,2,1,k4), e = LD4(R,0,1,k4); \
  float4 f = LD4(R,2,2,k4), g = LD4(R,0,2,k4); \
  P0 = ((v2f){a.x,a.y}-(v2f){b0.x,b0.y}) + two*((v2f){d.x,d.y}-(v2f){e.x,e.y}) + ((v2f){f.x,f.y}-(v2f){g.x,g.y}); \
  P1 = ((v2f){a.z,a.w}-(v2f){b0.z,b0.w}) + two*((v2f){d.z,d.w}-(v2f){e.z,e.w}) + ((v2f){f.z,f.w}-(v2f){g.z,g.w}); }

// layer-1 fma step k (named scalars via token paste)
#define MK(k) { v2f w0 = wx[k], w1v = wx[8+k]; \
  hA01 = __builtin_elementwise_fma(xpa##k, w0,  hA01); \
  hA23 = __builtin_elementwise_fma(ppa##k, w1v, hA23); \
  hB01 = __builtin_elementwise_fma(xpb##k, w0,  hB01); \
  hB23 = __builtin_elementwise_fma(ppb##k, w1v, hB23); }

// layer-2 fma step k
#define L2K(k) { v2f wv = w2p[k]; \
  acA##k = __builtin_elementwise_fma(hAv, wv, acA##k); \
  acB##k = __builtin_elementwise_fma(hBv, wv, acB##k); }

// full per-hidden-unit body; WX = weight-row pointer expression
#define MLP_ONE_N(WX) { \
  const v2f* wx = (WX); \
  float c1n = c1b[n]; \
  v2f hA01 = (v2f){c1n, 0.f}, hA23 = (v2f){0.f, 0.f}; \
  v2f hB01 = (v2f){c1n, 0.f}, hB23 = (v2f){0.f, 0.f}; \
  MK(0) MK(1) MK(2) MK(3) MK(4) MK(5) MK(6) MK(7) \
  float hvA = fmaxf((hA01.x + hA01.y) + (hA23.x + hA23.y), 0.f); \
  float hvB = fmaxf((hB01.x + hB01.y) + (hB23.x + hB23.y), 0.f); \
  v2f hAv = (v2f){hvA, hvA}, hBv = (v2f){hvB, hvB}; \
  const v2f* w2p = (const v2f*)(w2t + (n << 4)); \
  L2K(0) L2K(1) L2K(2) L2K(3) L2K(4) L2K(5) L2K(6) L2K(7) }

// reduction deposit / fold (named acc scalars)
#define DEP2(k) { RED2(q-2,2*k,px)=acA##k.x; RED2(q-2,2*k+1,px)=acA##k.y; \
                  RED2(q-2,2*k,px+64)=acB##k.x; RED2(q-2,2*k+1,px+64)=acB##k.y; }
#define FOLD2(k) { acA##k.x += RED2(q,2*k,px);    acA##k.y += RED2(q,2*k+1,px); \
                   acB##k.x += RED2(q,2*k,px+64); acB##k.y += RED2(q,2*k+1,px+64); }
#define DEPW(k) { RED2(q,2*k,px)=acA##k.x; RED2(q,2*k+1,px)=acA##k.y; \
                  RED2(q,2*k,px+64)=acB##k.x; RED2(q,2*k+1,px+64)=acB##k.y; }

// One NCA step. Block = 16x8 pixel tile x 4 hidden quarters (256 thr, q=wave,
// 2 pixels per lane: rows rA and rA+4).
// FIRST: X = input x (NCHW). Else: X = Yp*(Mp & living(Yp alpha)), Yp NHWC.
template<bool FIRST>
__global__ __launch_bounds__(NT, 2) void nca_step(
    const float* __restrict__ Xin,          // x (NCHW) if FIRST, else Y_{s-1} (NHWC)
    const unsigned char* __restrict__ Mp,   // M_{s-1} (ignored if FIRST)
    const float* __restrict__ w1eff, const float* __restrict__ w2t,
    const float* __restrict__ c1,
    uint32_t key0, uint32_t key1,
    float* __restrict__ Yn, unsigned char* __restrict__ Mn)  // Yn NHWC
{
  // monolithic carve: [xs 3600f][w1s 2048f]; red2[2][16][128] (4096f) aliases
  // the front (xs + w1s head) -- both dead after the MLP.
  __shared__ __align__(16) float sm[XS_F + W1S_F];   // 22592 B
  __shared__ float ya[STH+4][STW+4];    //   960 B: Y alpha + halo 2 (12x20)
  __shared__ float lifes[SHW][SWW];     //   720 B
  __shared__ float ufs[128];            //   512 B
  // total ~24.8 KB; 2 blocks/CU (VGPR cap 256) -> 512/576 resident

  float* w1s = sm + XS_F;
  #define RED2(bk,ch,p) sm[(((bk)*16+(ch))*128)+(p)]

  const int T = blockIdx.x;
  const int b = T & 7;                  // image == XCD (%8 round-robin heuristic)
  const int t = T >> 3;
  const int tw0 = (t % S_TILES_X)*STW, th0 = (t / S_TILES_X)*STH;
  const int tid = threadIdx.x;

  // ---- stage upper half of w1eff (units 64..127) -> LDS (2 float4/thread)
  {
    const float4* src = (const float4*)(w1eff + 64*32);
    float4* dst = (float4*)w1s;
    dst[tid]      = src[tid];
    dst[tid + NT] = src[tid + NT];
  }

  if (FIRST){
    // one-time: scalar stage from NCHW x into NHWC LDS
    for (int idx = tid; idx < CHN*SHW*SWW; idx += NT){
      int ch = idx / (SHW*SWW), rem = idx % (SHW*SWW);
      int hh = rem / SWW, ww = rem % SWW;
      int g2 = th0 - 1 + hh, w2 = tw0 - 1 + ww;
      float v = 0.f;
      if ((unsigned)g2 < NH && (unsigned)w2 < NW)
        v = Xin[((b*CHN + ch)*NH + g2)*NW + w2];
      sm[(hh*SWW + ww)*20 + ch] = v;
    }
    __syncthreads();
  } else {
    // Y alpha + halo 2 (zero-pad OOB: 0 <= 0.1 never flips the mask)
    if (tid < (STH+4)*(STW+4)){         // 240
      int hh = tid / (STW+4), ww = tid % (STW+4);
      int g2 = th0 - 2 + hh, w2 = tw0 - 2 + ww;
      float v = 0.f;
      if ((unsigned)g2 < NH && (unsigned)w2 < NW)
        v = Xin[(size_t)(b*PLANE + g2*NW + w2)*CHN + 3];
      ya[hh][ww] = v;
    }
    // coalesced float4 staging of Y tile+halo1 into NAMED regs
    // idx0=tid (<720 always), idx1=tid+256 (<720 always), idx2=tid+512 (guard)
    float4 xr0 = make_float4(0.f,0.f,0.f,0.f), xr1 = xr0, xr2 = xr0;
    #define STAGE_LD(XR, IDX, GUARD) { \
      int idx = (IDX); \
      if (!(GUARD) || idx < S_NF4){ \
        int hh = idx / (SWW*4); int rem = idx % (SWW*4); \
        int ww = rem >> 2, k4 = rem & 3; \
        int g2 = th0 - 1 + hh, w2 = tw0 - 1 + ww; \
        if ((unsigned)g2 < NH && (unsigned)w2 < NW) \
          XR = *(const float4*)(Xin + (size_t)(b*PLANE + g2*NW + w2)*CHN + k4*4); \
      } }
    STAGE_LD(xr0, tid,        0)
    STAGE_LD(xr1, tid + NT,   0)
    STAGE_LD(xr2, tid + 2*NT, 1)
    __syncthreads();                    // ya visible
    if (tid < SHW*SWW){                 // life over tile + halo 1 (180 elems)
      int hh = tid / SWW, ww = tid % SWW;
      int g2 = th0 - 1 + hh, w2 = tw0 - 1 + ww;
      float lf = 0.f;
      if ((unsigned)g2 < NH && (unsigned)w2 < NW){
        float mx = ya[hh][ww];
        #pragma unroll
        for (int dr = 0; dr < 3; ++dr)
          #pragma unroll
          for (int dc = 0; dc < 3; ++dc)
            mx = fmaxf(mx, ya[hh+dr][ww+dc]);
        lf = (Mp[b*PLANE + g2*NW + w2] && (mx > 0.1f)) ? 1.f : 0.f;
      }
      lifes[hh][ww] = lf;
    }
    __syncthreads();                    // lifes visible
    #define STAGE_ST(XR, IDX, GUARD) { \
      int idx = (IDX); \
      if (!(GUARD) || idx < S_NF4){ \
        int hh = idx / (SWW*4); int rem = idx % (SWW*4); \
        int ww = rem >> 2, k4 = rem & 3; \
        float lf = lifes[hh][ww]; \
        float4 v = XR; \
        v.x *= lf; v.y *= lf; v.z *= lf; v.w *= lf; \
        *(float4*)(sm + (hh*SWW + ww)*20 + k4*4) = v; \
      } }
    STAGE_ST(xr0, tid,        0)
    STAGE_ST(xr1, tid + NT,   0)
    STAGE_ST(xr2, tid + 2*NT, 1)
    __syncthreads();
  }

  const int px = tid & 63;          // lane pixel index (pixel A)
  const int q  = tid >> 6;          // hidden quarter == wave id (0..3)
  const int c = px & 15, rA = px >> 4;  // rA in 0..3; pixel B at row rA+4
  const int rB = rA + 4;
  const int gw = tw0 + c;
  const int posA = b*PLANE + (th0 + rA)*NW + gw;
  const int posB = posA + 4*NW;

  const v2f two = (v2f){2.f, 2.f};

  // ---- perception, all named scalars (no allocas anywhere)
  float4 xcA0 = LD4(rA,1,1,0), xcA1 = LD4(rA,1,1,1), xcA2 = LD4(rA,1,1,2), xcA3 = LD4(rA,1,1,3);
  float4 xcB0 = LD4(rB,1,1,0), xcB1 = LD4(rB,1,1,1), xcB2 = LD4(rB,1,1,2), xcB3 = LD4(rB,1,1,3);
  v2f xpa0 = (v2f){xcA0.x,xcA0.y}, xpa1 = (v2f){xcA0.z,xcA0.w};
  v2f xpa2 = (v2f){xcA1.x,xcA1.y}, xpa3 = (v2f){xcA1.z,xcA1.w};
  v2f xpa4 = (v2f){xcA2.x,xcA2.y}, xpa5 = (v2f){xcA2.z,xcA2.w};
  v2f xpa6 = (v2f){xcA3.x,xcA3.y}, xpa7 = (v2f){xcA3.z,xcA3.w};
  v2f xpb0 = (v2f){xcB0.x,xcB0.y}, xpb1 = (v2f){xcB0.z,xcB0.w};
  v2f xpb2 = (v2f){xcB1.x,xcB1.y}, xpb3 = (v2f){xcB1.z,xcB1.w};
  v2f xpb4 = (v2f){xcB2.x,xcB2.y}, xpb5 = (v2f){xcB2.z,xcB2.w};
  v2f xpb6 = (v2f){xcB3.x,xcB3.y}, xpb7 = (v2f){xcB3.z,xcB3.w};
  v2f ppa0, ppa1, ppa2, ppa3, ppa4, ppa5, ppa6, ppa7;
  v2f ppb0, ppb1, ppb2, ppb3, ppb4, ppb5, ppb6, ppb7;
  SXP(rA,0,ppa0,ppa1) SXP(rA,1,ppa2,ppa3) SYP(rA,2,ppa4,ppa5) SYP(rA,3,ppa6,ppa7)
  SXP(rB,0,ppb0,ppb1) SXP(rB,1,ppb2,ppb3) SYP(rB,2,ppb4,ppb5) SYP(rB,3,ppb6,ppb7)

  // threefry deduped to wave 0 (both px); M (pre_life of masked X alpha) wave 1
  if (q == 0){
    uint32_t o0, o1;
    threefry2x32(key0, key1, 0u, (uint32_t)posA, o0, o1);
    ufs[px]    = ((((o0 ^ o1) >> 31) == 0u) && (xcA0.w > 0.1f)) ? 1.f : 0.f;
    threefry2x32(key0, key1, 0u, (uint32_t)posB, o0, o1);
    ufs[px+64] = ((((o0 ^ o1) >> 31) == 0u) && (xcB0.w > 0.1f)) ? 1.f : 0.f;
  } else if (q == 1){
    float mxA = sm[(rA*SWW + c)*20 + 3];
    float mxB = sm[(rB*SWW + c)*20 + 3];
    #pragma unroll
    for (int dr = 0; dr < 3; ++dr)
      #pragma unroll
      for (int dc = 0; dc < 3; ++dc){
        mxA = fmaxf(mxA, sm[((rA+dr)*SWW + (c+dc))*20 + 3]);
        mxB = fmaxf(mxB, sm[((rB+dr)*SWW + (c+dc))*20 + 3]);
      }
    Mn[posA] = (mxA > 0.1f) ? (unsigned char)1 : (unsigned char)0;
    Mn[posB] = (mxB > 0.1f) ? (unsigned char)1 : (unsigned char)0;
  }

  // extract this wave's epilogue bases NOW (wave-uniform scalar select) so
  // the xc scalars die before the MLP
  const int qq = __builtin_amdgcn_readfirstlane(q);
  float4 myxA = xcA0, myxB = xcB0;
  if (qq == 1){ myxA = xcA1; myxB = xcB1; }
  else if (qq == 2){ myxA = xcA2; myxB = xcB2; }
  else if (qq == 3){ myxA = xcA3; myxB = xcB3; }

  // ---- packed MLP, SPLIT-PIPE weight streaming, 2 px/lane:
  //   waves 0-1 (units 0..63):  w1 rows via uniform GLOBAL reads -> s_load (K$)
  //   waves 2-3 (units 64..127): w1 rows via LDS broadcast (w1s upper half)
  // w2t + c1 via s_load for all waves. Wave-uniform branch, no divergence.
  v2f acA0 = (v2f){0.f,0.f}, acA1 = acA0, acA2 = acA0, acA3 = acA0,
      acA4 = acA0, acA5 = acA0, acA6 = acA0, acA7 = acA0;
  v2f acB0 = acA0, acB1 = acA0, acB2 = acA0, acB3 = acA0,
      acB4 = acA0, acB5 = acA0, acB6 = acA0, acB7 = acA0;
  const int nbase = qq << 5;
  const float* c1b = c1 + b*HIDN;

  if (qq < 2){
    #pragma unroll 2
    for (int nn = 0; nn < 32; ++nn){
      const int n = nbase + nn;
      MLP_ONE_N((const v2f*)(w1eff + (n << 5)))   // uniform addr -> s_load
    }
  } else {
    #pragma unroll 1
    for (int nn = 0; nn < 32; ++nn){
      const int n = nbase + nn;
      MLP_ONE_N((const v2f*)(w1s + ((n - 64) << 5)))  // LDS broadcast
    }
  }

  // sm (xs + w1s) dead from here; red2 aliases it (barrier makes reuse safe)
  __syncthreads();

  // ---- two-phase cross-wave reduction in the sm-aliased red2 (16KB)
  // phase 1: waves 2,3 deposit partials
  if (q >= 2){
    DEP2(0) DEP2(1) DEP2(2) DEP2(3) DEP2(4) DEP2(5) DEP2(6) DEP2(7)
  }
  __syncthreads();
  // phase 2: wave 0 folds wave 2's partials, wave 1 folds wave 3's; deposit
  if (q < 2){
    FOLD2(0) FOLD2(1) FOLD2(2) FOLD2(3) FOLD2(4) FOLD2(5) FOLD2(6) FOLD2(7)
    DEPW(0) DEPW(1) DEPW(2) DEPW(3) DEPW(4) DEPW(5) DEPW(6) DEPW(7)
  }
  __syncthreads();

  // epilogue: quarter q writes channels 4q..4q+3 as ONE float4 per pixel (NHWC)
  {
    float ufA = ufs[px], ufB = ufs[px+64];
    int ch = q << 2;
    float a0 = RED2(0, ch+0, px) + RED2(1, ch+0, px);
    float a1 = RED2(0, ch+1, px) + RED2(1, ch+1, px);
    float a2 = RED2(0, ch+2, px) + RED2(1, ch+2, px);
    float a3 = RED2(0, ch+3, px) + RED2(1, ch+3, px);
    float4 oA = make_float4(fmaf(a0, ufA, myxA.x), fmaf(a1, ufA, myxA.y),
                            fmaf(a2, ufA, myxA.z), fmaf(a3, ufA, myxA.w));
    *(float4*)(Yn + (size_t)posA*CHN + q*4) = oA;
    float b0 = RED2(0, ch+0, px+64) + RED2(1, ch+0, px+64);
    float b1v = RED2(0, ch+1, px+64) + RED2(1, ch+1, px+64);
    float b2 = RED2(0, ch+2, px+64) + RED2(1, ch+2, px+64);
    float b3 = RED2(0, ch+3, px+64) + RED2(1, ch+3, px+64);
    float4 oB = make_float4(fmaf(b0, ufB, myxB.x), fmaf(b1v, ufB, myxB.y),
                            fmaf(b2, ufB, myxB.z), fmaf(b3, ufB, myxB.w));
    *(float4*)(Yn + (size_t)posB*CHN + q*4) = oB;
  }
  #undef RED2
}

// Final: out (NCHW) = Y_63 (NHWC) * (M_63 & living(Y_63 alpha))
__global__ __launch_bounds__(256) void nca_final(
    const float* __restrict__ Yp, const unsigned char* __restrict__ Mp,
    float* __restrict__ out)
{
  __shared__ float ya[TH+4][TW+4];     // 8x20
  __shared__ float lifes[TH][TW];
  const int T = blockIdx.x;
  const int b = T & 7;
  const int t = T >> 3;
  const int tw0 = (t % TILES_X)*TW, th0 = (t / TILES_X)*TH;
  const int tid = threadIdx.x;
  if (tid < (TH+4)*(TW+4)){
    int hh = tid / (TW+4), ww = tid % (TW+4);
    int g2 = th0 - 2 + hh, w2 = tw0 - 2 + ww;
    float v = 0.f;
    if ((unsigned)g2 < NH && (unsigned)w2 < NW)
      v = Yp[(size_t)(b*PLANE + g2*NW + w2)*CHN + 3];
    ya[hh][ww] = v;
  }
  __syncthreads();
  if (tid < TH*TW){
    int i = tid >> 4, j = tid & 15;
    float mx = ya[i+2][j+2];
    #pragma unroll
    for (int dr = 0; dr < 3; ++dr)
      #pragma unroll
      for (int dc = 0; dc < 3; ++dc)
        mx = fmaxf(mx, ya[i+1+dr][j+1+dc]);
    lifes[i][j] = (Mp[b*PLANE + (th0+i)*NW + (tw0+j)] && (mx > 0.1f)) ? 1.f : 0.f;
  }
  __syncthreads();
  for (int idx = tid; idx < CHN*TH*TW; idx += 256){
    int ch = idx >> 6, p = idx & 63;
    int i = p >> 4, j = p & 15;
    int pos = b*PLANE + (th0+i)*NW + (tw0+j);
    out[((b*CHN + ch)*NH + th0 + i)*NW + tw0 + j] = Yp[(size_t)pos*CHN + ch] * lifes[i][j];
  }
}

extern "C" void kernel_launch(void* const* d_in, const int* in_sizes, int n_in,
                              void* d_out, int out_size, void* d_ws, size_t ws_size,
                              hipStream_t stream) {
  const float* x  = (const float*)d_in[0];
  const float* w  = (const float*)d_in[1];
  // d_in[2] = sobel (hard-coded), d_in[6] = steps (=64, hard-coded)
  const float* W1 = (const float*)d_in[3];
  const float* b1 = (const float*)d_in[4];
  const float* W2 = (const float*)d_in[5];
  float* out = (float*)d_out;
  char* ws = (char*)d_ws;

  size_t off = 0;
  float*    w1eff = (float*)(ws + off);    off += (size_t)HIDN*32*4;
  float*    w2t   = (float*)(ws + off);    off += (size_t)HIDN*CHN*4;
  float*    c1    = (float*)(ws + off);    off += (size_t)NB*HIDN*4;
  float*    Yb0   = (float*)(ws + off);    off += (size_t)NB*CHN*PLANE*4;  // NHWC
  float*    Yb1   = (float*)(ws + off);    off += (size_t)NB*CHN*PLANE*4;  // NHWC
  unsigned char* Mb0 = (unsigned char*)(ws + off); off += (size_t)NB*PLANE;
  unsigned char* Mb1 = (unsigned char*)(ws + off); off += (size_t)NB*PLANE;
  (void)ws_size; (void)in_sizes; (void)n_in; (void)out_size;

  // step keys are input-independent constants: compute on host, pass as args
  uint32_t k0[NSTEPS], k1[NSTEPS];
  for (int s = 0; s < NSTEPS; ++s) threefry2x32(0u, 42u, 0u, (uint32_t)s, k0[s], k1[s]);

  nca_pre<<<dim3(NB), dim3(256), 0, stream>>>(w, W1, b1, W2, w1eff, w2t, c1);

  nca_step<true><<<dim3(S_NBLK), dim3(NT), 0, stream>>>(
      x, Mb1 /*unused*/, w1eff, w2t, c1, k0[0], k1[0], Yb0, Mb0);
  for (int s = 1; s < NSTEPS; ++s){
    const float* Yp = (s & 1) ? Yb0 : Yb1;
    float*       Yn = (s & 1) ? Yb1 : Yb0;
    const unsigned char* Mq = (s & 1) ? Mb0 : Mb1;
    unsigned char*       Mn = (s & 1) ? Mb1 : Mb0;
    nca_step<false><<<dim3(S_NBLK), dim3(NT), 0, stream>>>(
        Yp, Mq, w1eff, w2t, c1, k0[s], k1[s], Yn, Mn);
  }
  // s=63 (odd) wrote Yb1/Mb1
  nca_final<<<dim3(NBLK), dim3(256), 0, stream>>>(Yb1, Mb1, out);
}